// Round 6
// baseline (94.771 us; speedup 1.0000x reference)
//
#include <hip/hip_runtime.h>
#include <hip/hip_bf16.h>
#include <math.h>

// Problem constants
#define BATCH   256
#define KMEM    10          // K (class size)
#define NPROT   200         // N*K prototypes per batch elem
#define DDIM    512
#define TINVF   10.0f       // 1/T
#define KSLAB   64          // K-columns staged per slab
#define NSLAB   (DDIM / KSLAB)   // 8
#define RPAD    256         // rows padded to 16 fragments
#define ROWB    128         // bytes per LDS row (64 bf16)
#define NSEG    800         // 200 rows x 4 segments of 16 floats
#define NBLK    (BATCH * 2) // 2 blocks per batch elem (row halves)

typedef __attribute__((ext_vector_type(8))) short short8;
typedef __attribute__((ext_vector_type(4))) float f32x4;

// bf16 round-to-nearest-even (finite inputs)
__device__ __forceinline__ unsigned short f2bf(float v) {
    unsigned u = __float_as_uint(v);
    return (unsigned short)((u + 0x7fffu + ((u >> 16) & 1u)) >> 16);
}

__device__ __forceinline__ void pack16(const float4 c[4], uint4& p0, uint4& p1, float& sq) {
    union { unsigned short us[16]; uint4 u[2]; } w;
    const float* f = (const float*)c;
    #pragma unroll
    for (int e = 0; e < 16; e++) {
        float v = f[e];
        sq = fmaf(v, v, sq);
        w.us[e] = f2bf(v);
    }
    p0 = w.u[0];
    p1 = w.u[1];
}

// Two blocks per batch element (row halves of the Gram). 512 threads = 8 waves
// in a 2x4 fragment grid; each wave computes 4x4 16x16 fragments of its strip.
// G_raw = Praw . Praw^T via MFMA on bf16; normalization, diagonal skip, class
// masks, exp/log in the epilogue.
__global__ __launch_bounds__(512, 4) void kmain(const float* __restrict__ P,
                                                float* __restrict__ partial) {
    __shared__ char  slab[2][RPAD * ROWB];   // 64 KB, XOR-swizzled bf16 tiles
    __shared__ float normpart[NSEG];
    __shared__ float invn_s[RPAD];
    __shared__ float s1buf[4][128];
    __shared__ float s2buf[4][128];
    __shared__ float red[512];

    const int tid  = threadIdx.x;
    const int lane = tid & 63;
    const int wave = tid >> 6;   // 0..7
    const int wrh  = wave >> 2;  // 0..1 : i-frags [wrh*4, wrh*4+4) of the strip
    const int wcq  = wave & 3;   // 0..3 : j-frags [wcq*4, wcq*4+4)
    const int b    = blockIdx.x >> 1;
    const int h    = blockIdx.x & 1;    // row half: strip rows [h*128, h*128+128)
    const float* Pb = P + (size_t)b * NPROT * DDIM;

    // zero pad rows 200..255 in BOTH buffers (never rewritten)
    for (int z = tid; z < 2 * 56 * 8; z += 512) {
        int bsel = z / (56 * 8);
        int slot = z % (56 * 8);
        int row  = NPROT + (slot >> 3);
        *(uint4*)(&slab[bsel][row * ROWB + (slot & 7) * 16]) = make_uint4(0, 0, 0, 0);
    }

    // staging assignment: seg idx -> (row, 16-float segment)
    const int  idx0 = tid;                 // < 800 always
    const int  row0 = idx0 >> 2, seg0 = idx0 & 3;
    const int  idx1 = tid + 512;
    const bool has1 = (idx1 < NSEG);       // threads 0..287
    const int  row1 = idx1 >> 2, seg1 = idx1 & 3;

    float sq0 = 0.f, sq1 = 0.f;

    // prefetch slab 0
    float4 curA[4], curB[4];
    {
        const float4* sA = (const float4*)(Pb + (size_t)row0 * DDIM + seg0 * 16);
        curA[0] = sA[0]; curA[1] = sA[1]; curA[2] = sA[2]; curA[3] = sA[3];
        if (has1) {
            const float4* sB = (const float4*)(Pb + (size_t)row1 * DDIM + seg1 * 16);
            curB[0] = sB[0]; curB[1] = sB[1]; curB[2] = sB[2]; curB[3] = sB[3];
        }
    }

    f32x4 acc[4][4];
    #pragma unroll
    for (int i = 0; i < 4; i++)
        #pragma unroll
        for (int j = 0; j < 4; j++)
            acc[i][j] = (f32x4)(0.f);

    const int swz0 = (row0 & 7) << 4;
    const int swz1 = (row1 & 7) << 4;

    for (int s = 0; s < NSLAB; s++) {
        char* buf = slab[s & 1];

        // ---- convert + swizzled LDS write + sumsq ----
        {
            uint4 p0, p1;
            pack16(curA, p0, p1, sq0);
            int byte0 = row0 * ROWB + seg0 * 32;
            *(uint4*)(&buf[(byte0     ) ^ swz0]) = p0;
            *(uint4*)(&buf[(byte0 + 16) ^ swz0]) = p1;
        }
        if (has1) {
            uint4 p0, p1;
            pack16(curB, p0, p1, sq1);
            int byte0 = row1 * ROWB + seg1 * 32;
            *(uint4*)(&buf[(byte0     ) ^ swz1]) = p0;
            *(uint4*)(&buf[(byte0 + 16) ^ swz1]) = p1;
        }
        __syncthreads();

        // ---- prefetch next slab (overlaps MFMA below) ----
        float4 nxtA[4], nxtB[4];
        if (s + 1 < NSLAB) {
            const float4* sA = (const float4*)(Pb + (size_t)row0 * DDIM + (s + 1) * KSLAB + seg0 * 16);
            nxtA[0] = sA[0]; nxtA[1] = sA[1]; nxtA[2] = sA[2]; nxtA[3] = sA[3];
            if (has1) {
                const float4* sB = (const float4*)(Pb + (size_t)row1 * DDIM + (s + 1) * KSLAB + seg1 * 16);
                nxtB[0] = sB[0]; nxtB[1] = sB[1]; nxtB[2] = sB[2]; nxtB[3] = sB[3];
            }
        }

        // ---- MFMA: 2 k-steps of 32 over this slab ----
        #pragma unroll
        for (int ks = 0; ks < 2; ks++) {
            const int kb = (ks * 32 + (lane >> 4) * 8) * 2;  // byte offset of k-chunk
            short8 af[4], bfr[4];
            #pragma unroll
            for (int i = 0; i < 4; i++) {
                int row = (h * 8 + wrh * 4 + i) * 16 + (lane & 15);
                af[i] = *(const short8*)(&buf[(row * ROWB + kb) ^ ((row & 7) << 4)]);
            }
            #pragma unroll
            for (int j = 0; j < 4; j++) {
                int row = (wcq * 4 + j) * 16 + (lane & 15);
                bfr[j] = *(const short8*)(&buf[(row * ROWB + kb) ^ ((row & 7) << 4)]);
            }
            #pragma unroll
            for (int j = 0; j < 4; j++)
                #pragma unroll
                for (int i = 0; i < 4; i++)
                    acc[i][j] = __builtin_amdgcn_mfma_f32_16x16x32_bf16(af[i], bfr[j], acc[i][j], 0, 0, 0);
        }

        #pragma unroll
        for (int q = 0; q < 4; q++) { curA[q] = nxtA[q]; curB[q] = nxtB[q]; }
    }

    // ---- norms: 4 seg-partials per row -> invn ----
    normpart[idx0] = sq0;
    if (has1) normpart[idx1] = sq1;
    __syncthreads();
    if (tid < RPAD) {
        float iv = 0.f;
        if (tid < NPROT) {
            float ns = normpart[4 * tid] + normpart[4 * tid + 1]
                     + normpart[4 * tid + 2] + normpart[4 * tid + 3];
            iv = rsqrtf(ns);
        }
        invn_s[tid] = iv;   // 0 for padded rows -> g stays 0
    }
    __syncthreads();

    // ---- epilogue: normalize, mask, exp/class sums, 16-lane reduce ----
    float ijn[4]; int jg[4], jdiv[4];
    #pragma unroll
    for (int j = 0; j < 4; j++) {
        jg[j]   = wcq * 64 + j * 16 + (lane & 15);
        ijn[j]  = invn_s[jg[j]];
        jdiv[j] = jg[j] / KMEM;
    }
    #pragma unroll
    for (int i = 0; i < 4; i++) {
        #pragma unroll
        for (int r = 0; r < 4; r++) {
            const int m = h * 128 + wrh * 64 + i * 16 + (lane >> 4) * 4 + r;
            const float im = invn_s[m];
            const int mdiv = m / KMEM;
            float s1 = 0.f, s2 = 0.f;
            #pragma unroll
            for (int j = 0; j < 4; j++) {
                float g = acc[i][j][r] * im * ijn[j];
                bool valid = (jg[j] < NPROT) && (m < NPROT) && (jg[j] != m);
                s1 += valid ? __expf(g * TINVF) : 0.f;
                s2 += (valid && (jdiv[j] == mdiv)) ? g : 0.f;
            }
            #pragma unroll
            for (int d = 1; d < 16; d <<= 1) {
                s1 += __shfl_xor(s1, d);
                s2 += __shfl_xor(s2, d);
            }
            if ((lane & 15) == 0) {
                s1buf[wcq][m - h * 128] = s1;
                s2buf[wcq][m - h * 128] = s2;
            }
        }
    }
    __syncthreads();

    // ---- per-anchor loss + block reduction ----
    float v = 0.f;
    if (tid < 128) {
        const int m = h * 128 + tid;
        if (m < NPROT) {
            float S1 = s1buf[0][tid] + s1buf[1][tid] + s1buf[2][tid] + s1buf[3][tid];
            float S2 = s2buf[0][tid] + s2buf[1][tid] + s2buf[2][tid] + s2buf[3][tid];
            v = logf(S1) - S2 * (TINVF / 9.0f);   // /(T*(K-1))
        }
    }
    red[tid] = v;
    __syncthreads();
    for (int sx = 256; sx > 0; sx >>= 1) {
        if (tid < sx) red[tid] += red[tid + sx];
        __syncthreads();
    }
    if (tid == 0) partial[blockIdx.x] = red[0];
}

// final reduction of 512 block partials (fp64) + scale
__global__ __launch_bounds__(256) void kfinal(const float* __restrict__ partial,
                                              float* __restrict__ out) {
    __shared__ double red[256];
    int tid = threadIdx.x;
    red[tid] = (double)partial[tid] + (double)partial[tid + 256];
    __syncthreads();
    for (int sx = 128; sx > 0; sx >>= 1) {
        if (tid < sx) red[tid] += red[tid + sx];
        __syncthreads();
    }
    // ALPHA / (BNORM * N * K * D) = 0.1 / 102400
    if (tid == 0) out[0] = (float)(red[0] * (0.1 / 102400.0));
}

extern "C" void kernel_launch(void* const* d_in, const int* in_sizes, int n_in,
                              void* d_out, int out_size, void* d_ws, size_t ws_size,
                              hipStream_t stream) {
    const float* P = (const float*)d_in[0];
    float* partial = (float*)d_ws;   // 512 floats
    float* out     = (float*)d_out;

    kmain<<<NBLK, 512, 0, stream>>>(P, partial);
    kfinal<<<1, 256, 0, stream>>>(partial, out);
}

// Round 7
// 40.183 us; speedup vs baseline: 2.3585x; 2.3585x over previous
//
#include <hip/hip_runtime.h>
#include <hip/hip_bf16.h>
#include <math.h>

// Problem constants
#define BATCH   256
#define KMEM    10          // K (class size)
#define NPROT   200         // N*K prototypes per batch elem
#define DDIM    512
#define TINVF   10.0f       // 1/T
#define KSLAB   64          // K-columns staged per slab
#define NSLAB   (DDIM / KSLAB)   // 8
#define RPAD    256         // rows padded to 16 fragments
#define ROWB    128         // bytes per LDS row (64 bf16)
#define NSEG    800         // 200 rows x 4 segments of 16 floats

typedef __attribute__((ext_vector_type(8))) short short8;
typedef __attribute__((ext_vector_type(4))) float f32x4;

// bf16 round-to-nearest-even (finite inputs)
__device__ __forceinline__ unsigned short f2bf(float v) {
    unsigned u = __float_as_uint(v);
    return (unsigned short)((u + 0x7fffu + ((u >> 16) & 1u)) >> 16);
}

__device__ __forceinline__ void pack16(const float4 c[4], uint4& p0, uint4& p1, float& sq) {
    union { unsigned short us[16]; uint4 u[2]; } w;
    const float* f = (const float*)c;
    #pragma unroll
    for (int e = 0; e < 16; e++) {
        float v = f[e];
        sq = fmaf(v, v, sq);
        w.us[e] = f2bf(v);
    }
    p0 = w.u[0];
    p1 = w.u[1];
}

// One block per batch element, 1024 threads = 16 waves (4x4 wave grid),
// each wave computes a 64x64 strip (4x4 fragments of 16x16) of the padded
// 256x256 Gram. G_raw = Praw . Praw^T via MFMA on bf16; normalization,
// diagonal skip, class masks, exp/log in the epilogue.
// NOTE: no second __launch_bounds__ arg — on this toolchain it acts as
// min-BLOCKS-per-CU and strangled VGPRs to 64 (scratch spills, round 6).
__global__ __launch_bounds__(1024) void kmain(const float* __restrict__ P,
                                              float* __restrict__ partial) {
    __shared__ char  slab[2][RPAD * ROWB];   // 64 KB, XOR-swizzled bf16 tiles
    __shared__ float normpart[NSEG];
    __shared__ float invn_s[RPAD];
    __shared__ float s1buf[4][RPAD];
    __shared__ float s2buf[4][RPAD];
    __shared__ float red[1024];

    const int tid  = threadIdx.x;
    const int lane = tid & 63;
    const int wave = tid >> 6;   // 0..15
    const int wr   = wave >> 2;  // 0..3 : i-frags [wr*4, wr*4+4)  (rows wr*64..)
    const int wc   = wave & 3;   // 0..3 : j-frags [wc*4, wc*4+4)  (cols wc*64..)
    const int b    = blockIdx.x;
    const float* Pb = P + (size_t)b * NPROT * DDIM;

    // zero pad rows 200..255 in BOTH buffers (never rewritten)
    if (tid < 2 * 56 * 8) {
        int bsel = tid / (56 * 8);
        int slot = tid % (56 * 8);
        int row  = NPROT + (slot >> 3);
        *(uint4*)(&slab[bsel][row * ROWB + (slot & 7) * 16]) = make_uint4(0, 0, 0, 0);
    }

    // staging assignment: one 16-float segment per thread (threads 0..799)
    const bool has0 = (tid < NSEG);
    const int  row0 = tid >> 2, seg0 = tid & 3;
    const int  swz0 = (row0 & 7) << 4;

    float sq0 = 0.f;

    // prefetch slab 0
    float4 curA[4];
    if (has0) {
        const float4* sA = (const float4*)(Pb + (size_t)row0 * DDIM + seg0 * 16);
        curA[0] = sA[0]; curA[1] = sA[1]; curA[2] = sA[2]; curA[3] = sA[3];
    }

    f32x4 acc[4][4];
    #pragma unroll
    for (int i = 0; i < 4; i++)
        #pragma unroll
        for (int j = 0; j < 4; j++)
            acc[i][j] = (f32x4)(0.f);

    for (int s = 0; s < NSLAB; s++) {
        char* buf = slab[s & 1];

        // ---- convert + swizzled LDS write + sumsq ----
        if (has0) {
            uint4 p0, p1;
            pack16(curA, p0, p1, sq0);
            int byte0 = row0 * ROWB + seg0 * 32;
            *(uint4*)(&buf[(byte0     ) ^ swz0]) = p0;
            *(uint4*)(&buf[(byte0 + 16) ^ swz0]) = p1;
        }
        __syncthreads();

        // ---- prefetch next slab (overlaps MFMA below) ----
        float4 nxtA[4];
        if (has0 && s + 1 < NSLAB) {
            const float4* sA = (const float4*)(Pb + (size_t)row0 * DDIM + (s + 1) * KSLAB + seg0 * 16);
            nxtA[0] = sA[0]; nxtA[1] = sA[1]; nxtA[2] = sA[2]; nxtA[3] = sA[3];
        }

        // ---- MFMA: 2 k-steps of 32 over this slab ----
        #pragma unroll
        for (int ks = 0; ks < 2; ks++) {
            const int kb = (ks * 32 + (lane >> 4) * 8) * 2;  // byte offset of k-chunk
            short8 af[4];
            #pragma unroll
            for (int i = 0; i < 4; i++) {
                int row = (wr * 4 + i) * 16 + (lane & 15);
                af[i] = *(const short8*)(&buf[(row * ROWB + kb) ^ ((row & 7) << 4)]);
            }
            #pragma unroll
            for (int j = 0; j < 4; j++) {
                int row = (wc * 4 + j) * 16 + (lane & 15);
                short8 bfr = *(const short8*)(&buf[(row * ROWB + kb) ^ ((row & 7) << 4)]);
                #pragma unroll
                for (int i = 0; i < 4; i++)
                    acc[i][j] = __builtin_amdgcn_mfma_f32_16x16x32_bf16(af[i], bfr, acc[i][j], 0, 0, 0);
            }
        }

        #pragma unroll
        for (int q = 0; q < 4; q++) curA[q] = nxtA[q];
    }

    // ---- norms: 4 seg-partials per row -> invn ----
    if (has0) normpart[tid] = sq0;
    __syncthreads();
    if (tid < RPAD) {
        float iv = 0.f;
        if (tid < NPROT) {
            float ns = normpart[4 * tid] + normpart[4 * tid + 1]
                     + normpart[4 * tid + 2] + normpart[4 * tid + 3];
            iv = rsqrtf(ns);
        }
        invn_s[tid] = iv;   // 0 for padded rows -> g stays 0
    }
    __syncthreads();

    // ---- epilogue: normalize, mask, exp/class sums, 16-lane reduce ----
    float ijn[4]; int jg[4], jdiv[4];
    #pragma unroll
    for (int j = 0; j < 4; j++) {
        jg[j]   = wc * 64 + j * 16 + (lane & 15);
        ijn[j]  = invn_s[jg[j]];
        jdiv[j] = jg[j] / KMEM;
    }
    #pragma unroll
    for (int i = 0; i < 4; i++) {
        #pragma unroll
        for (int r = 0; r < 4; r++) {
            const int m = wr * 64 + i * 16 + (lane >> 4) * 4 + r;
            const float im = invn_s[m];
            const int mdiv = m / KMEM;
            float s1 = 0.f, s2 = 0.f;
            #pragma unroll
            for (int j = 0; j < 4; j++) {
                float g = acc[i][j][r] * im * ijn[j];
                bool valid = (jg[j] < NPROT) && (m < NPROT) && (jg[j] != m);
                s1 += valid ? __expf(g * TINVF) : 0.f;
                s2 += (valid && (jdiv[j] == mdiv)) ? g : 0.f;
            }
            #pragma unroll
            for (int d = 1; d < 16; d <<= 1) {
                s1 += __shfl_xor(s1, d);
                s2 += __shfl_xor(s2, d);
            }
            if ((lane & 15) == 0) {
                s1buf[wc][m] = s1;
                s2buf[wc][m] = s2;
            }
        }
    }
    __syncthreads();

    // ---- per-anchor loss + block reduction ----
    float v = 0.f;
    if (tid < NPROT) {
        float S1 = s1buf[0][tid] + s1buf[1][tid] + s1buf[2][tid] + s1buf[3][tid];
        float S2 = s2buf[0][tid] + s2buf[1][tid] + s2buf[2][tid] + s2buf[3][tid];
        v = logf(S1) - S2 * (TINVF / 9.0f);   // /(T*(K-1))
    }
    red[tid] = v;
    __syncthreads();
    for (int sx = 512; sx > 0; sx >>= 1) {
        if (tid < sx) red[tid] += red[tid + sx];
        __syncthreads();
    }
    if (tid == 0) partial[b] = red[0];
}

// final reduction of 256 block partials (fp64) + scale
__global__ __launch_bounds__(256) void kfinal(const float* __restrict__ partial,
                                              float* __restrict__ out) {
    __shared__ double red[256];
    int tid = threadIdx.x;
    red[tid] = (double)partial[tid];
    __syncthreads();
    for (int sx = 128; sx > 0; sx >>= 1) {
        if (tid < sx) red[tid] += red[tid + sx];
        __syncthreads();
    }
    // ALPHA / (BNORM * N * K * D) = 0.1 / 102400
    if (tid == 0) out[0] = (float)(red[0] * (0.1 / 102400.0));
}

extern "C" void kernel_launch(void* const* d_in, const int* in_sizes, int n_in,
                              void* d_out, int out_size, void* d_ws, size_t ws_size,
                              hipStream_t stream) {
    const float* P = (const float*)d_in[0];
    float* partial = (float*)d_ws;   // 256 floats
    float* out     = (float*)d_out;

    kmain<<<BATCH, 1024, 0, stream>>>(P, partial);
    kfinal<<<1, 256, 0, stream>>>(partial, out);
}